// Round 1
// baseline (987.727 us; speedup 1.0000x reference)
//
#include <hip/hip_runtime.h>
#include <math.h>

#ifndef M_PI
#define M_PI 3.14159265358979323846
#endif

// Problem constants
constexpr int  NB   = 8;
constexpr int  CH   = 256;
constexpr long HW   = 4096;                 // 64*64
constexpr long SLOT = (long)NB * CH * HW;   // 8,388,608 floats per [8,256,64,64] tensor

// ---------------------------------------------------------------------------
// Tiled SGEMM:  C[b] (MxN) = A[b] (MxK) * B[b] (KxN)   (or B is [N,K] if BT)
// Tile 128(M) x 64(N), BK=16, 256 threads, 8x4 microtile per thread.
// EPI 0: bias (nullable) + store.  EPI 1: atomicAdd (split-K accumulate).
// EPI 2: cfr->mix fused epilogue: mix = beta*(cfr*(Q - lam*V) + V) + (1-beta)*Fw
// ---------------------------------------------------------------------------
template<bool BT, int EPI>
__global__ __launch_bounds__(256)
void gemm_kernel(const float* __restrict__ A, const float* __restrict__ B,
                 float* __restrict__ C, const float* __restrict__ bias,
                 int M, int N, int K, int nSplitK,
                 long aStride, long bStride, long cStride,
                 const float* __restrict__ qb, const float* __restrict__ vb,
                 const float* __restrict__ fwb,
                 const float* __restrict__ lambd, const float* __restrict__ beta)
{
  __shared__ __align__(16) float As[16][132];   // [k][m], pad -> 2-way max (free)
  __shared__ __align__(16) float Bs[16][68];    // [k][n]
  const int tid = threadIdx.x;
  const int b   = blockIdx.z / nSplitK;
  const int ks  = blockIdx.z % nSplitK;
  const int kLen = K / nSplitK;
  const int k0b  = ks * kLen;
  const float* Ab = A + (long)b * aStride;
  const float* Bb = B + (long)b * bStride;
  float* Cb = C + (long)b * cStride;
  const int m0 = blockIdx.y * 128;
  const int n0 = blockIdx.x * 64;

  float acc[8][4];
#pragma unroll
  for (int i = 0; i < 8; ++i)
#pragma unroll
    for (int j = 0; j < 4; ++j) acc[i][j] = 0.f;

  const int tx = tid & 15;   // load: k index   | compute: n quad
  const int ty = tid >> 4;   // load: row group | compute: m octet

  for (int kt = 0; kt < kLen; kt += 16) {
    const int k0 = k0b + kt;
#pragma unroll
    for (int q = 0; q < 8; ++q) {
      const int m = ty + q * 16;
      As[tx][m] = Ab[(long)(m0 + m) * K + (k0 + tx)];
    }
    if (BT) {
#pragma unroll
      for (int q = 0; q < 4; ++q) {
        const int n = ty + q * 16;
        Bs[tx][n] = Bb[(long)(n0 + n) * K + (k0 + tx)];
      }
    } else {
      const int n = tid & 63, j2 = tid >> 6;
#pragma unroll
      for (int q = 0; q < 4; ++q) {
        const int j3 = j2 + q * 4;
        Bs[j3][n] = Bb[(long)(k0 + j3) * N + (n0 + n)];
      }
    }
    __syncthreads();
#pragma unroll
    for (int kk = 0; kk < 16; ++kk) {
      const float4 a0 = *(const float4*)&As[kk][ty * 8];
      const float4 a1 = *(const float4*)&As[kk][ty * 8 + 4];
      const float4 b4 = *(const float4*)&Bs[kk][tx * 4];
      const float av[8] = {a0.x, a0.y, a0.z, a0.w, a1.x, a1.y, a1.z, a1.w};
      const float bv[4] = {b4.x, b4.y, b4.z, b4.w};
#pragma unroll
      for (int i = 0; i < 8; ++i)
#pragma unroll
        for (int j = 0; j < 4; ++j)
          acc[i][j] = fmaf(av[i], bv[j], acc[i][j]);
    }
    __syncthreads();
  }

  if (EPI == 0) {
#pragma unroll
    for (int i = 0; i < 8; ++i) {
      const int row = m0 + ty * 8 + i;
      const float bb = bias ? bias[row] : 0.f;
      float4 r;
      r.x = acc[i][0] + bb; r.y = acc[i][1] + bb;
      r.z = acc[i][2] + bb; r.w = acc[i][3] + bb;
      *(float4*)&Cb[(long)row * N + n0 + tx * 4] = r;
    }
  } else if (EPI == 1) {
#pragma unroll
    for (int i = 0; i < 8; ++i) {
      const int row = m0 + ty * 8 + i;
      float* p = &Cb[(long)row * N + n0 + tx * 4];
      atomicAdd(p + 0, acc[i][0]);
      atomicAdd(p + 1, acc[i][1]);
      atomicAdd(p + 2, acc[i][2]);
      atomicAdd(p + 3, acc[i][3]);
    }
  } else {
    const float lam = lambd[0], bet = beta[0];
#pragma unroll
    for (int i = 0; i < 8; ++i) {
      const int row = m0 + ty * 8 + i;
      const long off = (long)row * N + n0 + tx * 4;
      const long gi  = (long)b * cStride + off;
      const float4 qv = *(const float4*)&qb[gi];
      const float4 vv = *(const float4*)&vb[gi];
      const float4 fv = *(const float4*)&fwb[gi];
      float4 r;
      r.x = bet * (acc[i][0] * (qv.x - lam * vv.x) + vv.x) + (1.f - bet) * fv.x;
      r.y = bet * (acc[i][1] * (qv.y - lam * vv.y) + vv.y) + (1.f - bet) * fv.y;
      r.z = bet * (acc[i][2] * (qv.z - lam * vv.z) + vv.z) + (1.f - bet) * fv.z;
      r.w = bet * (acc[i][3] * (qv.w - lam * vv.w) + vv.w) + (1.f - bet) * fv.w;
      *(float4*)&Cb[off] = r;
    }
  }
}

// ---------------------------------------------------------------------------
// pooled[b,c] = mean over HW of (FR + FN)
// ---------------------------------------------------------------------------
__global__ __launch_bounds__(256)
void pool_kernel(const float* __restrict__ FR, const float* __restrict__ FN,
                 float* __restrict__ pooled)
{
  __shared__ float red[256];
  const int bc = blockIdx.x, tid = threadIdx.x;
  const float4* a = (const float4*)(FR + (long)bc * HW);
  const float4* b = (const float4*)(FN + (long)bc * HW);
  float s = 0.f;
  for (int v = tid; v < 1024; v += 256) {
    const float4 x = a[v]; s += x.x + x.y + x.z + x.w;
    const float4 y = b[v]; s += y.x + y.y + y.z + y.w;
  }
  red[tid] = s; __syncthreads();
  for (int o = 128; o > 0; o >>= 1) {
    if (tid < o) red[tid] += red[tid + o];
    __syncthreads();
  }
  if (tid == 0) pooled[bc] = red[0] * (1.f / 4096.f);
}

// ---------------------------------------------------------------------------
// MLP (relu) + 2-way softmax -> attn2 [8,2,256]
// ---------------------------------------------------------------------------
__global__ __launch_bounds__(256)
void attn2_kernel(const float* __restrict__ pooled, const float* __restrict__ w1,
                  const float* __restrict__ w2, float* __restrict__ attn2)
{
  __shared__ float ps[256];
  __shared__ float hs[32];
  const int b = blockIdx.x, tid = threadIdx.x;
  ps[tid] = pooled[b * 256 + tid];
  __syncthreads();
  if (tid < 32) {
    float a = 0.f;
    for (int c = 0; c < 256; ++c) a += ps[c] * w1[tid * 256 + c];
    hs[tid] = fmaxf(a, 0.f);
  }
  __syncthreads();
  float a0 = 0.f, a1 = 0.f;
  for (int d = 0; d < 32; ++d) {
    const float h = hs[d];
    a0 += h * w2[tid * 32 + d];
    a1 += h * w2[(256 + tid) * 32 + d];
  }
  const float m  = fmaxf(a0, a1);
  const float e0 = expf(a0 - m), e1 = expf(a1 - m);
  const float inv = 1.f / (e0 + e1);
  attn2[b * 512 + tid]       = e0 * inv;
  attn2[b * 512 + 256 + tid] = e1 * inv;
}

// ---------------------------------------------------------------------------
// Fw = a0*FR + a1*FN
// ---------------------------------------------------------------------------
__global__ __launch_bounds__(256)
void fw_kernel(const float* __restrict__ FR, const float* __restrict__ FN,
               const float* __restrict__ attn2, float* __restrict__ FW)
{
  const int b = blockIdx.z, c = blockIdx.y;
  const float a0 = attn2[b * 512 + c];
  const float a1 = attn2[b * 512 + 256 + c];
  const long base4 = ((long)b * 256 + c) * 1024;
  const int i = blockIdx.x * 256 + threadIdx.x;
  const float4 r = ((const float4*)FR)[base4 + i];
  const float4 n = ((const float4*)FN)[base4 + i];
  float4 o;
  o.x = a0 * r.x + a1 * n.x;
  o.y = a0 * r.y + a1 * n.y;
  o.z = a0 * r.z + a1 * n.z;
  o.w = a0 * r.w + a1 * n.w;
  ((float4*)FW)[base4 + i] = o;
}

// ---------------------------------------------------------------------------
// Depthwise 3x3, SAME padding. Optionally also writes the index-reversed copy
// (out_rev[(-y)%64, (-x)%64] = val) used by the attention-logits GEMM.
// ---------------------------------------------------------------------------
__global__ __launch_bounds__(256)
void dw_kernel(const float* __restrict__ in, const float* __restrict__ w,
               const float* __restrict__ bias, float* __restrict__ out,
               float* __restrict__ out_rev)
{
  __shared__ float img[66][66];
  const int bc = blockIdx.x, tid = threadIdx.x;
  const int c = bc & 255;
  for (int v = tid; v < 66 * 66; v += 256) ((float*)img)[v] = 0.f;
  __syncthreads();
  const float4* in4 = (const float4*)(in + (long)bc * HW);
  for (int v = tid; v < 1024; v += 256) {
    const float4 x = in4[v];
    const int r = v >> 4, c0 = ((v & 15) << 2) + 1;
    img[r + 1][c0 + 0] = x.x;
    img[r + 1][c0 + 1] = x.y;
    img[r + 1][c0 + 2] = x.z;
    img[r + 1][c0 + 3] = x.w;
  }
  float wr[9];
#pragma unroll
  for (int j = 0; j < 9; ++j) wr[j] = w[c * 9 + j];
  const float bb = bias[c];
  __syncthreads();
  for (int p = tid; p < 4096; p += 256) {
    const int y = p >> 6, x = p & 63;
    float s = bb;
#pragma unroll
    for (int ky = 0; ky < 3; ++ky)
#pragma unroll
      for (int kx = 0; kx < 3; ++kx)
        s = fmaf(wr[ky * 3 + kx], img[y + ky][x + kx], s);
    out[(long)bc * HW + p] = s;
    if (out_rev)
      out_rev[(long)bc * HW + (((64 - y) & 63) << 6) + ((64 - x) & 63)] = s;
  }
}

// ---------------------------------------------------------------------------
// S[b,c] = circconv2(Q[b,c], K[b,c]) = ifft2(fft2(Q) * fft2(K)), real.
// One block per (b,c) image. Forward = radix-2 DIF (bit-reversed output, no
// reorder needed), pointwise product in bit-reversed coords, inverse = radix-2
// DIT (consumes bit-reversed input, natural output). XOR-swizzled LDS so both
// row and column passes are bank-conflict free. LDS = 2 * 32KB = 64KB.
// ---------------------------------------------------------------------------
#define SW(r, c) (((r) << 6) | ((c) ^ ((r) & 31)))

__global__ __launch_bounds__(256)
void sconv_kernel(const float* __restrict__ Qg, const float* __restrict__ Kg,
                  float* __restrict__ Sg)
{
  __shared__ float2 FA[4096];
  __shared__ float2 FB[4096];
  const int tid = threadIdx.x;
  const long base = (long)blockIdx.x * 4096;

  for (int v = tid; v < 1024; v += 256) {
    const float4 q = ((const float4*)(Qg + base))[v];
    const float4 k = ((const float4*)(Kg + base))[v];
    const int r = v >> 4, c0 = (v & 15) << 2;
    FA[SW(r, c0 + 0)] = make_float2(q.x, 0.f);
    FA[SW(r, c0 + 1)] = make_float2(q.y, 0.f);
    FA[SW(r, c0 + 2)] = make_float2(q.z, 0.f);
    FA[SW(r, c0 + 3)] = make_float2(q.w, 0.f);
    FB[SW(r, c0 + 0)] = make_float2(k.x, 0.f);
    FB[SW(r, c0 + 1)] = make_float2(k.y, 0.f);
    FB[SW(r, c0 + 2)] = make_float2(k.z, 0.f);
    FB[SW(r, c0 + 3)] = make_float2(k.w, 0.f);
  }
  __syncthreads();

  // forward DIF on both arrays: pass 0 = rows, pass 1 = cols
  for (int pass = 0; pass < 2; ++pass) {
    for (int s = 5; s >= 0; --s) {
      const int h = 1 << s;
      for (int t = tid; t < 4096; t += 256) {
        float2* arr = (t & 2048) ? FB : FA;
        const int tt = t & 2047;
        const int line = tt >> 5, k = tt & 31;
        const int j  = k & (h - 1);
        const int i0 = ((k >> s) << (s + 1)) | j;
        const int i1 = i0 + h;
        const int e  = j << (5 - s);
        float sw, cw;
        __sincosf(-(float)M_PI * (float)e * (1.f / 32.f), &sw, &cw);
        const int a0 = pass ? SW(i0, line) : SW(line, i0);
        const int a1 = pass ? SW(i1, line) : SW(line, i1);
        const float2 u = arr[a0];
        const float2 v = arr[a1];
        arr[a0] = make_float2(u.x + v.x, u.y + v.y);
        const float dr = u.x - v.x, di = u.y - v.y;
        arr[a1] = make_float2(dr * cw - di * sw, dr * sw + di * cw);
      }
      __syncthreads();
    }
  }

  // pointwise complex product (identical physical permutation on both arrays)
  for (int v = tid; v < 4096; v += 256) {
    const float2 a = FA[v], b = FB[v];
    FA[v] = make_float2(a.x * b.x - a.y * b.y, a.x * b.y + a.y * b.x);
  }
  __syncthreads();

  // inverse DIT: pass 0 = cols, pass 1 = rows
  for (int pass = 0; pass < 2; ++pass) {
    for (int s = 0; s <= 5; ++s) {
      const int h = 1 << s;
      for (int t = tid; t < 2048; t += 256) {
        const int line = t >> 5, k = t & 31;
        const int j  = k & (h - 1);
        const int i0 = ((k >> s) << (s + 1)) | j;
        const int i1 = i0 + h;
        const int e  = j << (5 - s);
        float sw, cw;
        __sincosf((float)M_PI * (float)e * (1.f / 32.f), &sw, &cw);
        const int a0 = pass ? SW(line, i0) : SW(i0, line);
        const int a1 = pass ? SW(line, i1) : SW(i1, line);
        const float2 u = FA[a0];
        const float2 v = FA[a1];
        const float tr = v.x * cw - v.y * sw;
        const float ti = v.x * sw + v.y * cw;
        FA[a0] = make_float2(u.x + tr, u.y + ti);
        FA[a1] = make_float2(u.x - tr, u.y - ti);
      }
      __syncthreads();
    }
  }

  for (int v = tid; v < 1024; v += 256) {
    const int r = v >> 4, c0 = (v & 15) << 2;
    float4 o;
    o.x = FA[SW(r, c0 + 0)].x * (1.f / 4096.f);
    o.y = FA[SW(r, c0 + 1)].x * (1.f / 4096.f);
    o.z = FA[SW(r, c0 + 2)].x * (1.f / 4096.f);
    o.w = FA[SW(r, c0 + 3)].x * (1.f / 4096.f);
    ((float4*)(Sg + base))[v] = o;
  }
}

// ---------------------------------------------------------------------------
// row-wise softmax over d of |L| * 4096/alpha  (L holds the raw Q.Krev GEMM)
// ---------------------------------------------------------------------------
__global__ __launch_bounds__(256)
void softmax_kernel(float* __restrict__ L, const float* __restrict__ alpha)
{
  __shared__ float red[256];
  const int row = blockIdx.x, tid = threadIdx.x;
  const float sc = 4096.f / alpha[0];
  float* p = L + (long)row * 256;
  const float v = fabsf(p[tid]) * sc;
  red[tid] = v; __syncthreads();
  for (int o = 128; o > 0; o >>= 1) {
    if (tid < o) red[tid] = fmaxf(red[tid], red[tid + o]);
    __syncthreads();
  }
  const float mx = red[0];
  __syncthreads();
  const float e = expf(v - mx);
  red[tid] = e; __syncthreads();
  for (int o = 128; o > 0; o >>= 1) {
    if (tid < o) red[tid] += red[tid + o];
    __syncthreads();
  }
  p[tid] = e / red[0];
}

// ---------------------------------------------------------------------------
extern "C" void kernel_launch(void* const* d_in, const int* in_sizes, int n_in,
                              void* d_out, int out_size, void* d_ws, size_t ws_size,
                              hipStream_t stream)
{
  const float* x1       = (const float*)d_in[0];
  const float* x2       = (const float*)d_in[1];
  const float* conv_r_w = (const float*)d_in[2];
  const float* conv_r_b = (const float*)d_in[3];
  const float* conv_n_w = (const float*)d_in[4];
  const float* conv_n_b = (const float*)d_in[5];
  const float* mlp_w1   = (const float*)d_in[6];
  const float* mlp_w2   = (const float*)d_in[7];
  const float* pq_w     = (const float*)d_in[8];
  const float* pq_b     = (const float*)d_in[9];
  const float* dq_w     = (const float*)d_in[10];
  const float* dq_b     = (const float*)d_in[11];
  const float* pk_w     = (const float*)d_in[12];
  const float* pk_b     = (const float*)d_in[13];
  const float* dk_w     = (const float*)d_in[14];
  const float* dk_b     = (const float*)d_in[15];
  const float* pv_w     = (const float*)d_in[16];
  const float* pv_b     = (const float*)d_in[17];
  const float* dv_w     = (const float*)d_in[18];
  const float* dv_b     = (const float*)d_in[19];
  const float* out_w    = (const float*)d_in[20];
  const float* out_b    = (const float*)d_in[21];
  const float* alpha    = (const float*)d_in[22];
  const float* lambd    = (const float*)d_in[23];
  const float* beta     = (const float*)d_in[24];

  float* s = (float*)d_ws;
  float* S0 = s;             // FR  -> Q
  float* S1 = s + SLOT;      // FN  -> K
  float* S2 = s + 2 * SLOT;  // Fw  -> mix (in-place)
  float* S3 = s + 3 * SLOT;  // Pq  -> Krev
  float* S4 = s + 4 * SLOT;  // Pk  -> V
  float* S5 = s + 5 * SLOT;  // Pv  -> S
  float* Lb     = s + 6 * SLOT;          // [8,256,256]
  float* pooled = Lb + (long)8 * 256 * 256;
  float* attn2  = pooled + 2048;

  const size_t needed = (size_t)(6 * SLOT + 8L * 256 * 256 + 2048 + 4096) * sizeof(float);
  if (ws_size < needed) return;  // fail visibly rather than corrupt memory

  const long ST  = (long)CH * HW;   // 1048576, batch stride of [8,256,64,64]
  const long ST2 = (long)128 * HW;  // x2 batch stride
  const long STL = (long)256 * 256; // L batch stride

  hipMemsetAsync(Lb, 0, (size_t)8 * 256 * 256 * sizeof(float), stream);

  // FR = conv_r(x1), FN = conv_n(x2)
  gemm_kernel<false, 0><<<dim3(64, 2, 8), 256, 0, stream>>>(
      conv_r_w, x1, S0, conv_r_b, 256, 4096, 256, 1, 0L, ST, ST,
      nullptr, nullptr, nullptr, nullptr, nullptr);
  gemm_kernel<false, 0><<<dim3(64, 2, 8), 256, 0, stream>>>(
      conv_n_w, x2, S1, conv_n_b, 256, 4096, 128, 1, 0L, ST2, ST,
      nullptr, nullptr, nullptr, nullptr, nullptr);

  pool_kernel<<<2048, 256, 0, stream>>>(S0, S1, pooled);
  attn2_kernel<<<8, 256, 0, stream>>>(pooled, mlp_w1, mlp_w2, attn2);
  fw_kernel<<<dim3(4, 256, 8), 256, 0, stream>>>(S0, S1, attn2, S2);

  // Pq/Pk/Pv = 1x1 convs of Fw
  gemm_kernel<false, 0><<<dim3(64, 2, 8), 256, 0, stream>>>(
      pq_w, S2, S3, pq_b, 256, 4096, 256, 1, 0L, ST, ST,
      nullptr, nullptr, nullptr, nullptr, nullptr);
  gemm_kernel<false, 0><<<dim3(64, 2, 8), 256, 0, stream>>>(
      pk_w, S2, S4, pk_b, 256, 4096, 256, 1, 0L, ST, ST,
      nullptr, nullptr, nullptr, nullptr, nullptr);
  gemm_kernel<false, 0><<<dim3(64, 2, 8), 256, 0, stream>>>(
      pv_w, S2, S5, pv_b, 256, 4096, 256, 1, 0L, ST, ST,
      nullptr, nullptr, nullptr, nullptr, nullptr);

  // depthwise 3x3: Q <- Pq, K <- Pk (+ reversed copy), V <- Pv
  dw_kernel<<<2048, 256, 0, stream>>>(S3, dq_w, dq_b, S0, nullptr);  // Q  -> S0
  dw_kernel<<<2048, 256, 0, stream>>>(S4, dk_w, dk_b, S1, S3);       // K  -> S1, Krev -> S3
  dw_kernel<<<2048, 256, 0, stream>>>(S5, dv_w, dv_b, S4, nullptr);  // V  -> S4

  // S = circconv2(Q, K) per channel
  sconv_kernel<<<2048, 256, 0, stream>>>(S0, S1, S5);                // S -> S5

  // attn logits: L = Q . Krev  (split-K=16, fp32 atomic accumulate)
  gemm_kernel<true, 1><<<dim3(4, 2, 128), 256, 0, stream>>>(
      S0, S3, Lb, nullptr, 256, 256, 4096, 16, ST, ST, STL,
      nullptr, nullptr, nullptr, nullptr, nullptr);

  softmax_kernel<<<2048, 256, 0, stream>>>(Lb, alpha);

  // cfr = attn_w @ S, fused: mix = beta*(cfr*(Q-lam*V)+V)+(1-beta)*Fw  (in S2)
  gemm_kernel<false, 2><<<dim3(64, 2, 8), 256, 0, stream>>>(
      Lb, S5, S2, nullptr, 256, 4096, 256, 1, STL, ST, ST,
      S0, S4, S2, lambd, beta);

  // final 1x1 conv -> d_out
  gemm_kernel<false, 0><<<dim3(64, 2, 8), 256, 0, stream>>>(
      out_w, S2, (float*)d_out, out_b, 256, 4096, 256, 1, 0L, ST, ST,
      nullptr, nullptr, nullptr, nullptr, nullptr);
}